// Round 4
// baseline (126.847 us; speedup 1.0000x reference)
//
#include <hip/hip_runtime.h>
#include <hip/hip_cooperative_groups.h>
#include <math.h>

namespace cg = cooperative_groups;

#define N_G   4096
#define IMW   96
#define IMH   96
#define TILES_X 6
#define NTILE 36                 // 6x6 tiles of 16x16 px
#define NSTAGE 16                // 4096 / 256 gaussians per stage
#define FXI   (1.0f/96.0f)
#define FYI   (1.0f/96.0f)
#define NEARP 0.3f
#define EPSV  1e-8f
#define LOG2E 1.4426950408889634f

// One cooperative kernel, 256 blocks x 256 threads (1 block/CU, co-resident).
// P1: preprocess (blocks 0..15) -> P2: rank-by-count (all blocks) ->
// P3: scatter to sorted AoS (blocks 0..15) -> P4: per-tile cull+composite
// (blocks 0..35, writes final image).
__global__ __launch_bounds__(256, 1) void splat_all(
    const float* __restrict__ pos, const float* __restrict__ rgb,
    const float* __restrict__ opa, const float* __restrict__ quat,
    const float* __restrict__ scale, const float* __restrict__ rot,
    const float* __restrict__ tran,
    float* __restrict__ key, int* __restrict__ rank,
    float4* __restrict__ un4, float4* __restrict__ ucull,
    float4* __restrict__ so4, float4* __restrict__ scull,
    float* __restrict__ out)
{
    cg::grid_group grid = cg::this_grid();
    const int b = blockIdx.x, t = threadIdx.x;

    __shared__ unsigned long long sk[256];        // P2
    __shared__ float4 g0[256], g1[256], g2[256];  // P4 compacted gaussians
    __shared__ int wsum[4];                        // P4 per-wave ballot counts

    // ---------------- P1: preprocess ----------------
    if (b < 16) {
        int i = b * 256 + t;

        float R00=rot[0],R01=rot[1],R02=rot[2];
        float R10=rot[3],R11=rot[4],R12=rot[5];
        float R20=rot[6],R21=rot[7],R22=rot[8];
        float t0=tran[0], t1=tran[1], t2=tran[2];

        float p0 = pos[i*3+0], p1 = pos[i*3+1], p2 = pos[i*3+2];
        float x = R00*p0 + R01*p1 + R02*p2 + t0;
        float y = R10*p0 + R11*p1 + R12*p2 + t1;
        float z = R20*p0 + R21*p1 + R22*p2 + t2;
        float rr = sqrtf(x*x + y*y + z*z);
        float invz = 1.0f / z;
        float mu = x * invz, mv = y * invz;

        float J00 = invz,  J02 = -x*invz*invz;
        float J11 = invz,  J12 = -y*invz*invz;
        float JW00 = J00*R00 + J02*R20;
        float JW01 = J00*R01 + J02*R21;
        float JW02 = J00*R02 + J02*R22;
        float JW10 = J11*R10 + J12*R20;
        float JW11 = J11*R11 + J12*R21;
        float JW12 = J11*R12 + J12*R22;

        float qw = quat[i*4+0], qx = quat[i*4+1], qy = quat[i*4+2], qz = quat[i*4+3];
        float qn = sqrtf(qw*qw+qx*qx+qy*qy+qz*qz) + 1e-12f;
        float qi = 1.0f/qn;
        qw*=qi; qx*=qi; qy*=qi; qz*=qi;
        float Q00 = 1.f-2.f*(qy*qy+qz*qz), Q01 = 2.f*(qx*qy - qw*qz), Q02 = 2.f*(qx*qz + qw*qy);
        float Q10 = 2.f*(qx*qy + qw*qz), Q11 = 1.f-2.f*(qx*qx+qz*qz), Q12 = 2.f*(qy*qz - qw*qx);
        float Q20 = 2.f*(qx*qz - qw*qy), Q21 = 2.f*(qy*qz + qw*qx), Q22 = 1.f-2.f*(qx*qx+qy*qy);

        float s0 = fabsf(scale[i*3+0]) + 1e-4f;
        float s1 = fabsf(scale[i*3+1]) + 1e-4f;
        float s2 = fabsf(scale[i*3+2]) + 1e-4f;
        float A00=Q00*s0, A01=Q01*s1, A02=Q02*s2;
        float A10=Q10*s0, A11=Q11*s1, A12=Q12*s2;
        float A20=Q20*s0, A21=Q21*s1, A22=Q22*s2;
        float C00 = A00*A00+A01*A01+A02*A02;
        float C01 = A00*A10+A01*A11+A02*A12;
        float C02 = A00*A20+A01*A21+A02*A22;
        float C11 = A10*A10+A11*A11+A12*A12;
        float C12 = A10*A20+A11*A21+A12*A22;
        float C22 = A20*A20+A21*A21+A22*A22;
        float M00 = JW00*C00 + JW01*C01 + JW02*C02;
        float M01 = JW00*C01 + JW01*C11 + JW02*C12;
        float M02 = JW00*C02 + JW01*C12 + JW02*C22;
        float M10 = JW10*C00 + JW11*C01 + JW12*C02;
        float M11 = JW10*C01 + JW11*C11 + JW12*C12;
        float M12 = JW10*C02 + JW11*C12 + JW12*C22;
        float a = M00*JW00 + M01*JW01 + M02*JW02 + EPSV;
        float d = M10*JW10 + M11*JW11 + M12*JW12 + EPSV;
        float bb = 0.5f*((M00*JW10 + M01*JW11 + M02*JW12) +
                         (M10*JW00 + M11*JW01 + M12*JW02));
        float invdet = 1.0f/(a*d - bb*bb);
        float iaP = -0.5f * d * invdet * LOG2E;
        float ibP =  bb * invdet * LOG2E;
        float idP = -0.5f * a * invdet * LOG2E;

        float sig_o = 1.0f/(1.0f + __expf(-opa[i]));
        float valid = (z > NEARP) ? 1.0f : 0.0f;
        float c0 = 1.0f/(1.0f+__expf(-rgb[i*3+0]));
        float c1 = 1.0f/(1.0f+__expf(-rgb[i*3+1]));
        float c2 = 1.0f/(1.0f+__expf(-rgb[i*3+2]));
        float opa_eff = sig_o * valid;

        // conservative cull radius^2 (log2 units): drop if alpha < opa*2^-34
        float q00 = -iaP, q01 = -0.5f*ibP, q11 = -idP;
        float df = q00 - q11;
        float lam = 0.5f*((q00 + q11) - sqrtf(df*df + 4.0f*q01*q01));
        lam = fmaxf(lam, 1e-20f);
        float cull_r2 = (34.0f + log2f(opa_eff)) / lam;

        key[i]  = rr;
        rank[i] = 0;
        un4[i*3+0] = make_float4(mu, mv, iaP, ibP);
        un4[i*3+1] = make_float4(idP, opa_eff, c0, c1);
        un4[i*3+2] = make_float4(c2, 0.0f, 0.0f, 0.0f);
        ucull[i]   = make_float4(mu, mv, cull_r2, 0.0f);
    }
    grid.sync();

    // ---------------- P2: rank by counting ----------------
    {
        int bx = b & 15, by = b >> 4;
        int gi = bx * 256 + t;      // gaussian ranked by this thread
        int kj = by * 256 + t;      // key staged by this thread
        sk[t] = ((unsigned long long)__float_as_uint(key[kj]) << 32) | (unsigned int)kj;
        __syncthreads();
        unsigned long long pk =
            ((unsigned long long)__float_as_uint(key[gi]) << 32) | (unsigned int)gi;
        int cnt = 0;
        #pragma unroll 8
        for (int j = 0; j < 256; j++) cnt += (sk[j] < pk) ? 1 : 0;
        atomicAdd(&rank[gi], cnt);
    }
    grid.sync();

    // ---------------- P3: scatter into sorted AoS ----------------
    if (b < 16) {
        int i = b * 256 + t;
        int r = rank[i];
        so4[r*3+0] = un4[i*3+0];
        so4[r*3+1] = un4[i*3+1];
        so4[r*3+2] = un4[i*3+2];
        scull[r]   = ucull[i];
    }
    grid.sync();

    // ---------------- P4: per-tile cull + compact + composite ----------------
    if (b < NTILE) {
        int tx = b % TILES_X, ty = b / TILES_X;
        float u0 = ((float)(tx*16) + 0.5f - 48.0f) * FXI;
        float u1 = u0 + 15.0f * FXI;
        float v0 = ((float)(ty*16) + 0.5f - 48.0f) * FYI;
        float v1 = v0 + 15.0f * FYI;

        int px = tx*16 + (t & 15);
        int py = ty*16 + (t >> 4);
        float pu = ((float)px + 0.5f - 48.0f) * FXI;
        float pv = ((float)py + 0.5f - 48.0f) * FYI;

        int wid = t >> 6, lane = t & 63;
        float T = 1.0f, cr = 0.0f, cg_ = 0.0f, cb = 0.0f;

        for (int st = 0; st < NSTAGE; st++) {
            int gi = st * 256 + t;
            float4 cq = scull[gi];
            float cu = fminf(fmaxf(cq.x, u0), u1);
            float cv = fminf(fmaxf(cq.y, v0), v1);
            float ddx = cq.x - cu, ddy = cq.y - cv;
            bool flag = (ddx*ddx + ddy*ddy) <= cq.z;   // false for -inf/NaN r2

            unsigned long long m = __ballot(flag);
            if (lane == 0) wsum[wid] = __popcll(m);
            __syncthreads();
            int total = wsum[0] + wsum[1] + wsum[2] + wsum[3];
            if (flag) {
                int base = 0;
                #pragma unroll
                for (int w = 0; w < 3; w++) base += (w < wid) ? wsum[w] : 0;
                int pos = base + __popcll(m & ((1ull << lane) - 1ull));
                g0[pos] = so4[gi*3+0];
                g1[pos] = so4[gi*3+1];
                g2[pos] = so4[gi*3+2];
            }
            __syncthreads();

            #pragma unroll 2
            for (int g = 0; g < total; g++) {
                float4 a0 = g0[g];
                float4 a1 = g1[g];
                float4 a2 = g2[g];
                float dx = pu - a0.x;
                float dy = pv - a0.y;
                float pw = dx*(a0.z*dx + a0.w*dy) + a1.x*dy*dy;  // log2-scaled
                float al = fminf(a1.y * __builtin_amdgcn_exp2f(pw), 0.99f);
                float w = T * al;
                cr  += w * a1.z;
                cg_ += w * a1.w;
                cb  += w * a2.x;
                T *= (1.0f - al);
            }
            // next stage's wsum/g writes are fenced by the barriers above
        }

        int pixel = py * IMW + px;
        out[pixel*3+0] = cr;
        out[pixel*3+1] = cg_;
        out[pixel*3+2] = cb;
    }
}

extern "C" void kernel_launch(void* const* d_in, const int* in_sizes, int n_in,
                              void* d_out, int out_size, void* d_ws, size_t ws_size,
                              hipStream_t stream) {
    const float* pos   = (const float*)d_in[0];
    const float* rgb   = (const float*)d_in[1];
    const float* opa   = (const float*)d_in[2];
    const float* quat  = (const float*)d_in[3];
    const float* scale = (const float*)d_in[4];
    const float* rot   = (const float*)d_in[5];
    const float* tran  = (const float*)d_in[6];
    float* out = (float*)d_out;

    float* ws      = (float*)d_ws;
    float*  key    = ws;                       // 4096 f
    int*    rank   = (int*)(ws + N_G);         // 4096 i
    float4* un4    = (float4*)(ws + 2*N_G);    // 4096*3 f4
    float4* ucull  = un4 + N_G*3;              // 4096 f4
    float4* so4    = ucull + N_G;              // 4096*3 f4
    float4* scull  = so4 + N_G*3;              // 4096 f4

    void* args[] = { (void*)&pos, (void*)&rgb, (void*)&opa, (void*)&quat,
                     (void*)&scale, (void*)&rot, (void*)&tran,
                     (void*)&key, (void*)&rank, (void*)&un4, (void*)&ucull,
                     (void*)&so4, (void*)&scull, (void*)&out };
    hipLaunchCooperativeKernel((void*)splat_all, dim3(256), dim3(256),
                               args, 0, stream);
}

// Round 5
// 49.631 us; speedup vs baseline: 2.5558x; 2.5558x over previous
//
#include <hip/hip_runtime.h>
#include <math.h>

#define N_G   4096
#define IMW   96
#define TILES_X 6
#define NTILE 36            // 6x6 tiles of 16x16 px
#define NSTAGE 16           // 4096 / 256 gaussians per cull stage
#define CAP   512           // max survivors per tile (data gives ~40-150)
#define FXI   (1.0f/96.0f)
#define NEARP 0.3f
#define EPSV  1e-8f
#define LOG2E 1.4426950408889634f

struct Cam { float R[9]; float t[3]; };
struct GParam { float mu, mv, iaP, ibP, idP, opa_eff, rr; };

// All projection / covariance math for one gaussian (colors excluded).
// Quadratic coeffs premultiplied by log2(e) so composite uses exp2 directly.
__device__ __forceinline__ GParam gauss_params(int gi,
    const float* __restrict__ pos, const float* __restrict__ opa,
    const float* __restrict__ quat, const float* __restrict__ scale,
    const Cam& C)
{
    float p0=pos[gi*3+0], p1=pos[gi*3+1], p2=pos[gi*3+2];
    float x = C.R[0]*p0 + C.R[1]*p1 + C.R[2]*p2 + C.t[0];
    float y = C.R[3]*p0 + C.R[4]*p1 + C.R[5]*p2 + C.t[1];
    float z = C.R[6]*p0 + C.R[7]*p1 + C.R[8]*p2 + C.t[2];
    float rr = sqrtf(x*x + y*y + z*z);
    float invz = 1.0f/z;
    float mu = x*invz, mv = y*invz;

    float J02 = -x*invz*invz, J12 = -y*invz*invz;
    float JW00 = invz*C.R[0] + J02*C.R[6];
    float JW01 = invz*C.R[1] + J02*C.R[7];
    float JW02 = invz*C.R[2] + J02*C.R[8];
    float JW10 = invz*C.R[3] + J12*C.R[6];
    float JW11 = invz*C.R[4] + J12*C.R[7];
    float JW12 = invz*C.R[5] + J12*C.R[8];

    float qw=quat[gi*4+0], qx=quat[gi*4+1], qy=quat[gi*4+2], qz=quat[gi*4+3];
    float qn = sqrtf(qw*qw+qx*qx+qy*qy+qz*qz) + 1e-12f;
    float qi = 1.0f/qn;
    qw*=qi; qx*=qi; qy*=qi; qz*=qi;
    float Q00=1.f-2.f*(qy*qy+qz*qz), Q01=2.f*(qx*qy-qw*qz), Q02=2.f*(qx*qz+qw*qy);
    float Q10=2.f*(qx*qy+qw*qz), Q11=1.f-2.f*(qx*qx+qz*qz), Q12=2.f*(qy*qz-qw*qx);
    float Q20=2.f*(qx*qz-qw*qy), Q21=2.f*(qy*qz+qw*qx), Q22=1.f-2.f*(qx*qx+qy*qy);

    float s0=fabsf(scale[gi*3+0])+1e-4f;
    float s1=fabsf(scale[gi*3+1])+1e-4f;
    float s2=fabsf(scale[gi*3+2])+1e-4f;
    float A00=Q00*s0,A01=Q01*s1,A02=Q02*s2;
    float A10=Q10*s0,A11=Q11*s1,A12=Q12*s2;
    float A20=Q20*s0,A21=Q21*s1,A22=Q22*s2;
    float C00=A00*A00+A01*A01+A02*A02;
    float C01=A00*A10+A01*A11+A02*A12;
    float C02=A00*A20+A01*A21+A02*A22;
    float C11=A10*A10+A11*A11+A12*A12;
    float C12=A10*A20+A11*A21+A12*A22;
    float C22=A20*A20+A21*A21+A22*A22;
    float M00=JW00*C00+JW01*C01+JW02*C02;
    float M01=JW00*C01+JW01*C11+JW02*C12;
    float M02=JW00*C02+JW01*C12+JW02*C22;
    float M10=JW10*C00+JW11*C01+JW12*C02;
    float M11=JW10*C01+JW11*C11+JW12*C12;
    float M12=JW10*C02+JW11*C12+JW12*C22;
    float a  = M00*JW00+M01*JW01+M02*JW02 + EPSV;
    float d  = M10*JW10+M11*JW11+M12*JW12 + EPSV;
    float bb = 0.5f*((M00*JW10+M01*JW11+M02*JW12)+(M10*JW00+M11*JW01+M12*JW02));
    float invdet = 1.0f/(a*d - bb*bb);

    GParam g;
    g.mu = mu; g.mv = mv;
    g.iaP = -0.5f*d*invdet*LOG2E;
    g.ibP =  bb*invdet*LOG2E;
    g.idP = -0.5f*a*invdet*LOG2E;
    float sig = 1.0f/(1.0f+__expf(-opa[gi]));
    g.opa_eff = (z > NEARP) ? sig : 0.0f;
    g.rr = rr;
    return g;
}

// One block per 16x16 tile. Cull -> compact -> local sort -> composite.
// No global sort, no workspace, no atomics, single launch.
__global__ __launch_bounds__(256) void splat_one(
    const float* __restrict__ pos, const float* __restrict__ rgb,
    const float* __restrict__ opa, const float* __restrict__ quat,
    const float* __restrict__ scale, const float* __restrict__ rot,
    const float* __restrict__ tran, float* __restrict__ out)
{
    __shared__ unsigned long long slist[CAP];   // survivors, original order
    __shared__ unsigned long long sorder[CAP];  // survivors, depth-sorted
    __shared__ float4 g0[CAP], g1[CAP], g2[CAP];
    __shared__ int wsum[4];

    const int t = threadIdx.x;
    const int tile = blockIdx.x;
    const int tx = tile % TILES_X, ty = tile / TILES_X;
    const float u0 = ((float)(tx*16) + 0.5f - 48.0f) * FXI;
    const float u1 = u0 + 15.0f * FXI;
    const float v0 = ((float)(ty*16) + 0.5f - 48.0f) * FXI;
    const float v1 = v0 + 15.0f * FXI;

    Cam C;
    #pragma unroll
    for (int k = 0; k < 9; k++) C.R[k] = rot[k];
    #pragma unroll
    for (int k = 0; k < 3; k++) C.t[k] = tran[k];

    const int wid = t >> 6, lane = t & 63;
    int cnt = 0;   // every thread tracks the same running survivor count

    // ---- phase 1: cull all gaussians against this tile, compact survivors ----
    for (int st = 0; st < NSTAGE; st++) {
        int gi = st*256 + t;
        GParam g = gauss_params(gi, pos, opa, quat, scale, C);

        // conservative cull radius^2 (log2 units): keep if alpha could
        // exceed opa * 2^-34 anywhere in the tile rect.
        float q00 = -g.iaP, q01 = -0.5f*g.ibP, q11 = -g.idP;
        float df = q00 - q11;
        float lam = 0.5f*((q00 + q11) - sqrtf(df*df + 4.0f*q01*q01));
        lam = fmaxf(lam, 1e-20f);
        float r2 = (34.0f + log2f(g.opa_eff)) / lam;  // -inf when opa_eff==0

        float cu = fminf(fmaxf(g.mu, u0), u1);
        float cv = fminf(fmaxf(g.mv, v0), v1);
        float ddx = g.mu - cu, ddy = g.mv - cv;
        bool flag = (ddx*ddx + ddy*ddy) <= r2;        // false for -inf/NaN

        unsigned long long m = __ballot(flag);
        if (lane == 0) wsum[wid] = __popcll(m);
        __syncthreads();
        int w0 = wsum[0], w1 = wsum[1], w2 = wsum[2], w3 = wsum[3];
        if (flag) {
            int base = cnt;
            if (wid > 0) base += w0;
            if (wid > 1) base += w1;
            if (wid > 2) base += w2;
            base += __popcll(m & ((1ull << lane) - 1ull));
            if (base < CAP)
                slist[base] = ((unsigned long long)__float_as_uint(g.rr) << 32)
                              | (unsigned int)gi;
        }
        cnt += w0 + w1 + w2 + w3;
        __syncthreads();   // protects wsum reuse and slist visibility
    }
    if (cnt > CAP) cnt = CAP;

    // ---- phase 2: local depth sort by (key_bits, idx) via rank-by-count ----
    for (int s = t; s < cnt; s += 256) {
        unsigned long long v = slist[s];
        int r = 0;
        for (int j = 0; j < cnt; j++) r += (slist[j] < v) ? 1 : 0;
        sorder[r] = v;
    }
    __syncthreads();

    // ---- phase 3: full params (incl. colors) for sorted survivors ----
    for (int s = t; s < cnt; s += 256) {
        int gi = (int)(sorder[s] & 0xffffffffu);
        GParam g = gauss_params(gi, pos, opa, quat, scale, C);
        float c0 = 1.0f/(1.0f+__expf(-rgb[gi*3+0]));
        float c1 = 1.0f/(1.0f+__expf(-rgb[gi*3+1]));
        float c2 = 1.0f/(1.0f+__expf(-rgb[gi*3+2]));
        g0[s] = make_float4(g.mu, g.mv, g.iaP, g.ibP);
        g1[s] = make_float4(g.idP, g.opa_eff, c0, c1);
        g2[s] = make_float4(c2, 0.0f, 0.0f, 0.0f);
    }
    __syncthreads();

    // ---- phase 4: per-pixel front-to-back composite ----
    int px = tx*16 + (t & 15);
    int py = ty*16 + (t >> 4);
    float pu = ((float)px + 0.5f - 48.0f) * FXI;
    float pv = ((float)py + 0.5f - 48.0f) * FXI;

    float T = 1.0f, cr = 0.0f, cg = 0.0f, cb = 0.0f;
    for (int s = 0; s < cnt; s++) {
        float4 a0 = g0[s];
        float4 a1 = g1[s];
        float4 a2 = g2[s];
        float dx = pu - a0.x;
        float dy = pv - a0.y;
        float pw = dx*(a0.z*dx + a0.w*dy) + a1.x*dy*dy;   // log2-scaled power
        float al = fminf(a1.y * __builtin_amdgcn_exp2f(pw), 0.99f);
        float w = T * al;
        cr += w * a1.z;
        cg += w * a1.w;
        cb += w * a2.x;
        T *= (1.0f - al);
    }

    int pixel = py * IMW + px;
    out[pixel*3+0] = cr;
    out[pixel*3+1] = cg;
    out[pixel*3+2] = cb;
}

extern "C" void kernel_launch(void* const* d_in, const int* in_sizes, int n_in,
                              void* d_out, int out_size, void* d_ws, size_t ws_size,
                              hipStream_t stream) {
    const float* pos   = (const float*)d_in[0];
    const float* rgb   = (const float*)d_in[1];
    const float* opa   = (const float*)d_in[2];
    const float* quat  = (const float*)d_in[3];
    const float* scale = (const float*)d_in[4];
    const float* rot   = (const float*)d_in[5];
    const float* tran  = (const float*)d_in[6];
    float* out = (float*)d_out;

    splat_one<<<NTILE, 256, 0, stream>>>(pos, rgb, opa, quat, scale, rot, tran, out);
}

// Round 6
// 30.825 us; speedup vs baseline: 4.1150x; 1.6101x over previous
//
#include <hip/hip_runtime.h>
#include <math.h>

#define N_G   4096
#define IMW   96
#define TILES_X 6
#define NTILE 36            // 6x6 tiles of 16x16 px
#define CAP   512           // max survivors per tile
#define FXI   (1.0f/96.0f)
#define NEARP 0.3f
#define EPSV  1e-8f
#define LOG2E 1.4426950408889634f
#define CULL_K 26.0f        // drop alpha < opa * 2^-26 within tile

// ---------------- K1: per-gaussian preprocessing (once, globally) ------------
// un4 slot0: {mu, mv, iaP, ibP}  slot1: {idP, opa_eff, cr, cg}  slot2: {cb,-,-,-}
// ucull:     {mu, mv, cull_r2, depth_key}
// quadratic coeffs premultiplied by log2(e) so composite uses exp2 directly.
__global__ __launch_bounds__(256) void preprocess_k(
    const float* __restrict__ pos, const float* __restrict__ rgb,
    const float* __restrict__ opa, const float* __restrict__ quat,
    const float* __restrict__ scale, const float* __restrict__ rot,
    const float* __restrict__ tran,
    float4* __restrict__ un4, float4* __restrict__ ucull)
{
    int i = blockIdx.x * blockDim.x + threadIdx.x;
    if (i >= N_G) return;

    float R00=rot[0],R01=rot[1],R02=rot[2];
    float R10=rot[3],R11=rot[4],R12=rot[5];
    float R20=rot[6],R21=rot[7],R22=rot[8];
    float t0=tran[0], t1=tran[1], t2=tran[2];

    float p0 = pos[i*3+0], p1 = pos[i*3+1], p2 = pos[i*3+2];
    float x = R00*p0 + R01*p1 + R02*p2 + t0;
    float y = R10*p0 + R11*p1 + R12*p2 + t1;
    float z = R20*p0 + R21*p1 + R22*p2 + t2;
    float rr = sqrtf(x*x + y*y + z*z);
    float invz = 1.0f / z;
    float mu = x * invz, mv = y * invz;

    float J02 = -x*invz*invz, J12 = -y*invz*invz;
    float JW00 = invz*R00 + J02*R20;
    float JW01 = invz*R01 + J02*R21;
    float JW02 = invz*R02 + J02*R22;
    float JW10 = invz*R10 + J12*R20;
    float JW11 = invz*R11 + J12*R21;
    float JW12 = invz*R12 + J12*R22;

    float qw = quat[i*4+0], qx = quat[i*4+1], qy = quat[i*4+2], qz = quat[i*4+3];
    float qn = sqrtf(qw*qw+qx*qx+qy*qy+qz*qz) + 1e-12f;
    float qi = 1.0f/qn;
    qw*=qi; qx*=qi; qy*=qi; qz*=qi;
    float Q00=1.f-2.f*(qy*qy+qz*qz), Q01=2.f*(qx*qy-qw*qz), Q02=2.f*(qx*qz+qw*qy);
    float Q10=2.f*(qx*qy+qw*qz), Q11=1.f-2.f*(qx*qx+qz*qz), Q12=2.f*(qy*qz-qw*qx);
    float Q20=2.f*(qx*qz-qw*qy), Q21=2.f*(qy*qz+qw*qx), Q22=1.f-2.f*(qx*qx+qy*qy);

    float s0=fabsf(scale[i*3+0])+1e-4f;
    float s1=fabsf(scale[i*3+1])+1e-4f;
    float s2=fabsf(scale[i*3+2])+1e-4f;
    float A00=Q00*s0,A01=Q01*s1,A02=Q02*s2;
    float A10=Q10*s0,A11=Q11*s1,A12=Q12*s2;
    float A20=Q20*s0,A21=Q21*s1,A22=Q22*s2;
    float C00=A00*A00+A01*A01+A02*A02;
    float C01=A00*A10+A01*A11+A02*A12;
    float C02=A00*A20+A01*A21+A02*A22;
    float C11=A10*A10+A11*A11+A12*A12;
    float C12=A10*A20+A11*A21+A12*A22;
    float C22=A20*A20+A21*A21+A22*A22;
    float M00=JW00*C00+JW01*C01+JW02*C02;
    float M01=JW00*C01+JW01*C11+JW02*C12;
    float M02=JW00*C02+JW01*C12+JW02*C22;
    float M10=JW10*C00+JW11*C01+JW12*C02;
    float M11=JW10*C01+JW11*C11+JW12*C12;
    float M12=JW10*C02+JW11*C12+JW12*C22;
    float a  = M00*JW00+M01*JW01+M02*JW02 + EPSV;
    float d  = M10*JW10+M11*JW11+M12*JW12 + EPSV;
    float bb = 0.5f*((M00*JW10+M01*JW11+M02*JW12)+(M10*JW00+M11*JW01+M12*JW02));
    float invdet = 1.0f/(a*d - bb*bb);
    float iaP = -0.5f*d*invdet*LOG2E;
    float ibP =  bb*invdet*LOG2E;
    float idP = -0.5f*a*invdet*LOG2E;

    float sig_o = 1.0f/(1.0f+__expf(-opa[i]));
    float opa_eff = (z > NEARP) ? sig_o : 0.0f;
    float c0 = 1.0f/(1.0f+__expf(-rgb[i*3+0]));
    float c1 = 1.0f/(1.0f+__expf(-rgb[i*3+1]));
    float c2 = 1.0f/(1.0f+__expf(-rgb[i*3+2]));

    // conservative cull radius^2 (log2 units): power <= -lam_min * dist^2
    float q00 = -iaP, q01 = -0.5f*ibP, q11 = -idP;
    float df = q00 - q11;
    float lam = 0.5f*((q00 + q11) - sqrtf(df*df + 4.0f*q01*q01));
    lam = fmaxf(lam, 1e-20f);
    float r2 = (CULL_K + log2f(opa_eff)) / lam;   // -inf when opa_eff==0

    un4[i*3+0] = make_float4(mu, mv, iaP, ibP);
    un4[i*3+1] = make_float4(idP, opa_eff, c0, c1);
    un4[i*3+2] = make_float4(c2, 0.0f, 0.0f, 0.0f);
    ucull[i]   = make_float4(mu, mv, r2, rr);
}

// ---------------- K2: per-tile cull + local sort + composite -----------------
// 36 blocks x 1024 threads (16 waves). Each pixel handled by 4 threads, each
// compositing a depth-contiguous quarter of the survivors; merged via LDS.
__global__ __launch_bounds__(1024, 1) void render_k(
    const float4* __restrict__ un4, const float4* __restrict__ ucull,
    float* __restrict__ out)
{
    __shared__ unsigned long long slist[CAP];   // survivors, original order
    __shared__ unsigned long long sorder[CAP];  // survivors, depth-sorted
    __shared__ float4 g0[CAP], g1[CAP], g2[CAP];
    __shared__ float4 pix[1024];
    __shared__ int wsum[16];

    const int t = threadIdx.x;
    const int tile = blockIdx.x;
    const int tx = tile % TILES_X, ty = tile / TILES_X;
    const float u0 = ((float)(tx*16) + 0.5f - 48.0f) * FXI;
    const float u1 = u0 + 15.0f * FXI;
    const float v0 = ((float)(ty*16) + 0.5f - 48.0f) * FXI;
    const float v1 = v0 + 15.0f * FXI;

    const int wid = t >> 6, lane = t & 63;
    int cnt = 0;

    // ---- cull + ballot-compact (4 stages x 1024 coalesced float4 loads) ----
    #pragma unroll
    for (int st = 0; st < 4; st++) {
        int gi = st*1024 + t;
        float4 cq = ucull[gi];
        float cu = fminf(fmaxf(cq.x, u0), u1);
        float cv = fminf(fmaxf(cq.y, v0), v1);
        float ddx = cq.x - cu, ddy = cq.y - cv;
        bool flag = (ddx*ddx + ddy*ddy) <= cq.z;    // false for -inf/NaN r2

        unsigned long long m = __ballot(flag);
        if (lane == 0) wsum[wid] = __popcll(m);
        __syncthreads();
        int base = cnt, tot = 0;
        #pragma unroll
        for (int w = 0; w < 16; w++) {
            int c = wsum[w];
            if (w < wid) base += c;
            tot += c;
        }
        if (flag) {
            int p = base + __popcll(m & ((1ull << lane) - 1ull));
            if (p < CAP)
                slist[p] = ((unsigned long long)__float_as_uint(cq.w) << 32)
                           | (unsigned int)gi;
        }
        cnt += tot;
        __syncthreads();
    }
    if (cnt > CAP) cnt = CAP;

    // ---- local depth sort by (key_bits, idx) via rank-by-count ----
    if (t < cnt) {
        unsigned long long v = slist[t];
        int r = 0;
        for (int j = 0; j < cnt; j++) r += (slist[j] < v) ? 1 : 0;
        sorder[r] = v;
    }
    __syncthreads();

    // ---- gather sorted survivor params ----
    if (t < cnt) {
        int gi = (int)(sorder[t] & 0xffffffffu);
        g0[t] = un4[gi*3+0];
        g1[t] = un4[gi*3+1];
        g2[t] = un4[gi*3+2];
    }
    __syncthreads();

    // ---- 4-way depth-segmented composite ----
    const int seg = t >> 8, pid = t & 255;
    const int px = tx*16 + (pid & 15);
    const int py = ty*16 + (pid >> 4);
    const float pu = ((float)px + 0.5f - 48.0f) * FXI;
    const float pv = ((float)py + 0.5f - 48.0f) * FXI;

    const int per = (cnt + 3) >> 2;
    const int sA = seg * per;
    const int sB = min(sA + per, cnt);

    float T = 1.0f, cr = 0.0f, cg = 0.0f, cb = 0.0f;
    #pragma unroll 2
    for (int s = sA; s < sB; s++) {
        float4 a0 = g0[s];
        float4 a1 = g1[s];
        float4 a2 = g2[s];
        float dx = pu - a0.x;
        float dy = pv - a0.y;
        float pw = dx*(a0.z*dx + a0.w*dy) + a1.x*dy*dy;   // log2-scaled power
        float al = fminf(a1.y * __builtin_amdgcn_exp2f(pw), 0.99f);
        float w = T * al;
        cr += w * a1.z;
        cg += w * a1.w;
        cb += w * a2.x;
        T *= (1.0f - al);
    }
    pix[t] = make_float4(cr, cg, cb, T);
    __syncthreads();

    if (t < 256) {
        float4 A = pix[t];
        float4 B = pix[256 + t];
        float4 Cc = pix[512 + t];
        float4 D = pix[768 + t];
        float orr = A.x + A.w*(B.x + B.w*(Cc.x + Cc.w*D.x));
        float og  = A.y + A.w*(B.y + B.w*(Cc.y + Cc.w*D.y));
        float ob  = A.z + A.w*(B.z + B.w*(Cc.z + Cc.w*D.z));
        int pixel = py * IMW + px;
        out[pixel*3+0] = orr;
        out[pixel*3+1] = og;
        out[pixel*3+2] = ob;
    }
}

extern "C" void kernel_launch(void* const* d_in, const int* in_sizes, int n_in,
                              void* d_out, int out_size, void* d_ws, size_t ws_size,
                              hipStream_t stream) {
    const float* pos   = (const float*)d_in[0];
    const float* rgb   = (const float*)d_in[1];
    const float* opa   = (const float*)d_in[2];
    const float* quat  = (const float*)d_in[3];
    const float* scale = (const float*)d_in[4];
    const float* rot   = (const float*)d_in[5];
    const float* tran  = (const float*)d_in[6];
    float* out = (float*)d_out;

    float4* un4   = (float4*)d_ws;      // 4096*3 float4
    float4* ucull = un4 + N_G*3;        // 4096 float4

    preprocess_k<<<N_G/256, 256, 0, stream>>>(pos, rgb, opa, quat, scale, rot, tran,
                                              un4, ucull);
    render_k<<<NTILE, 1024, 0, stream>>>(un4, ucull, out);
}

// Round 7
// 19.751 us; speedup vs baseline: 6.4222x; 1.5607x over previous
//
#include <hip/hip_runtime.h>
#include <math.h>

#define N_G   4096
#define IMW   96
#define TILE  8             // 8x8 px tiles
#define TILES_X 12
#define NTILE (TILES_X*TILES_X)   // 144
#define NTHR  512           // 8 waves per block
#define NSEG  8             // threads per pixel (depth segments)
#define CAP   512           // max survivors per tile
#define FXI   (1.0f/96.0f)
#define NEARP 0.3f
#define EPSV  1e-8f
#define LOG2E 1.4426950408889634f
#define CULL_K 26.0f        // drop alpha < opa * 2^-26 within tile

// ---------------- K1: per-gaussian preprocessing (once, globally) ------------
// un4 slot0: {mu, mv, iaP, ibP}  slot1: {idP, opa_eff, cr, cg}  slot2: {cb,-,-,-}
// ucull:     {mu, mv, cull_r2, depth_key}
// quadratic coeffs premultiplied by log2(e) so composite uses exp2 directly.
__global__ __launch_bounds__(256) void preprocess_k(
    const float* __restrict__ pos, const float* __restrict__ rgb,
    const float* __restrict__ opa, const float* __restrict__ quat,
    const float* __restrict__ scale, const float* __restrict__ rot,
    const float* __restrict__ tran,
    float4* __restrict__ un4, float4* __restrict__ ucull)
{
    int i = blockIdx.x * blockDim.x + threadIdx.x;
    if (i >= N_G) return;

    float R00=rot[0],R01=rot[1],R02=rot[2];
    float R10=rot[3],R11=rot[4],R12=rot[5];
    float R20=rot[6],R21=rot[7],R22=rot[8];
    float t0=tran[0], t1=tran[1], t2=tran[2];

    float p0 = pos[i*3+0], p1 = pos[i*3+1], p2 = pos[i*3+2];
    float x = R00*p0 + R01*p1 + R02*p2 + t0;
    float y = R10*p0 + R11*p1 + R12*p2 + t1;
    float z = R20*p0 + R21*p1 + R22*p2 + t2;
    float rr = sqrtf(x*x + y*y + z*z);
    float invz = 1.0f / z;
    float mu = x * invz, mv = y * invz;

    float J02 = -x*invz*invz, J12 = -y*invz*invz;
    float JW00 = invz*R00 + J02*R20;
    float JW01 = invz*R01 + J02*R21;
    float JW02 = invz*R02 + J02*R22;
    float JW10 = invz*R10 + J12*R20;
    float JW11 = invz*R11 + J12*R21;
    float JW12 = invz*R12 + J12*R22;

    float qw = quat[i*4+0], qx = quat[i*4+1], qy = quat[i*4+2], qz = quat[i*4+3];
    float qn = sqrtf(qw*qw+qx*qx+qy*qy+qz*qz) + 1e-12f;
    float qi = 1.0f/qn;
    qw*=qi; qx*=qi; qy*=qi; qz*=qi;
    float Q00=1.f-2.f*(qy*qy+qz*qz), Q01=2.f*(qx*qy-qw*qz), Q02=2.f*(qx*qz+qw*qy);
    float Q10=2.f*(qx*qy+qw*qz), Q11=1.f-2.f*(qx*qx+qz*qz), Q12=2.f*(qy*qz-qw*qx);
    float Q20=2.f*(qx*qz-qw*qy), Q21=2.f*(qy*qz+qw*qx), Q22=1.f-2.f*(qx*qx+qy*qy);

    float s0=fabsf(scale[i*3+0])+1e-4f;
    float s1=fabsf(scale[i*3+1])+1e-4f;
    float s2=fabsf(scale[i*3+2])+1e-4f;
    float A00=Q00*s0,A01=Q01*s1,A02=Q02*s2;
    float A10=Q10*s0,A11=Q11*s1,A12=Q12*s2;
    float A20=Q20*s0,A21=Q21*s1,A22=Q22*s2;
    float C00=A00*A00+A01*A01+A02*A02;
    float C01=A00*A10+A01*A11+A02*A12;
    float C02=A00*A20+A01*A21+A02*A22;
    float C11=A10*A10+A11*A11+A12*A12;
    float C12=A10*A20+A11*A21+A12*A22;
    float C22=A20*A20+A21*A21+A22*A22;
    float M00=JW00*C00+JW01*C01+JW02*C02;
    float M01=JW00*C01+JW01*C11+JW02*C12;
    float M02=JW00*C02+JW01*C12+JW02*C22;
    float M10=JW10*C00+JW11*C01+JW12*C02;
    float M11=JW10*C01+JW11*C11+JW12*C12;
    float M12=JW10*C02+JW11*C12+JW12*C22;
    float a  = M00*JW00+M01*JW01+M02*JW02 + EPSV;
    float d  = M10*JW10+M11*JW11+M12*JW12 + EPSV;
    float bb = 0.5f*((M00*JW10+M01*JW11+M02*JW12)+(M10*JW00+M11*JW01+M12*JW02));
    float invdet = 1.0f/(a*d - bb*bb);
    float iaP = -0.5f*d*invdet*LOG2E;
    float ibP =  bb*invdet*LOG2E;
    float idP = -0.5f*a*invdet*LOG2E;

    float sig_o = 1.0f/(1.0f+__expf(-opa[i]));
    float opa_eff = (z > NEARP) ? sig_o : 0.0f;
    float c0 = 1.0f/(1.0f+__expf(-rgb[i*3+0]));
    float c1 = 1.0f/(1.0f+__expf(-rgb[i*3+1]));
    float c2 = 1.0f/(1.0f+__expf(-rgb[i*3+2]));

    // conservative cull radius^2 (log2 units): power <= -lam_min * dist^2
    float q00 = -iaP, q01 = -0.5f*ibP, q11 = -idP;
    float df = q00 - q11;
    float lam = 0.5f*((q00 + q11) - sqrtf(df*df + 4.0f*q01*q01));
    lam = fmaxf(lam, 1e-20f);
    float r2 = (CULL_K + log2f(opa_eff)) / lam;   // -inf when opa_eff==0

    un4[i*3+0] = make_float4(mu, mv, iaP, ibP);
    un4[i*3+1] = make_float4(idP, opa_eff, c0, c1);
    un4[i*3+2] = make_float4(c2, 0.0f, 0.0f, 0.0f);
    ucull[i]   = make_float4(mu, mv, r2, rr);
}

// ---------------- K2: per-tile cull + local sort + composite -----------------
// 144 blocks (8x8 px tiles) x 512 threads. 8 threads per pixel, each
// compositing a depth-contiguous eighth of the survivors; merged via LDS.
__global__ __launch_bounds__(NTHR, 1) void render_k(
    const float4* __restrict__ un4, const float4* __restrict__ ucull,
    float* __restrict__ out)
{
    __shared__ unsigned long long slist[CAP];   // survivors, original order
    __shared__ unsigned long long sorder[CAP];  // survivors, depth-sorted
    __shared__ float4 g0[CAP], g1[CAP], g2[CAP];
    __shared__ float4 pix[NTHR];
    __shared__ int wsum[NTHR/64];

    const int t = threadIdx.x;
    const int tile = blockIdx.x;
    const int tx = tile % TILES_X, ty = tile / TILES_X;
    const float u0 = ((float)(tx*TILE) + 0.5f - 48.0f) * FXI;
    const float u1 = u0 + (TILE-1) * FXI;
    const float v0 = ((float)(ty*TILE) + 0.5f - 48.0f) * FXI;
    const float v1 = v0 + (TILE-1) * FXI;

    const int wid = t >> 6, lane = t & 63;
    int cnt = 0;

    // ---- cull + ballot-compact (8 stages x 512 coalesced float4 loads) ----
    #pragma unroll
    for (int st = 0; st < N_G/NTHR; st++) {
        int gi = st*NTHR + t;
        float4 cq = ucull[gi];
        float cu = fminf(fmaxf(cq.x, u0), u1);
        float cv = fminf(fmaxf(cq.y, v0), v1);
        float ddx = cq.x - cu, ddy = cq.y - cv;
        bool flag = (ddx*ddx + ddy*ddy) <= cq.z;    // false for -inf/NaN r2

        unsigned long long m = __ballot(flag);
        if (lane == 0) wsum[wid] = __popcll(m);
        __syncthreads();
        int base = cnt, tot = 0;
        #pragma unroll
        for (int w = 0; w < NTHR/64; w++) {
            int c = wsum[w];
            if (w < wid) base += c;
            tot += c;
        }
        if (flag) {
            int p = base + __popcll(m & ((1ull << lane) - 1ull));
            if (p < CAP)
                slist[p] = ((unsigned long long)__float_as_uint(cq.w) << 32)
                           | (unsigned int)gi;
        }
        cnt += tot;
        __syncthreads();
    }
    if (cnt > CAP) cnt = CAP;

    // ---- local depth sort by (key_bits, idx) via rank-by-count ----
    if (t < cnt) {
        unsigned long long v = slist[t];
        int r = 0;
        for (int j = 0; j < cnt; j++) r += (slist[j] < v) ? 1 : 0;
        sorder[r] = v;
    }
    __syncthreads();

    // ---- gather sorted survivor params ----
    if (t < cnt) {
        int gi = (int)(sorder[t] & 0xffffffffu);
        g0[t] = un4[gi*3+0];
        g1[t] = un4[gi*3+1];
        g2[t] = un4[gi*3+2];
    }
    __syncthreads();

    // ---- 8-way depth-segmented composite ----
    const int seg = t >> 6, pid = t & 63;          // seg in [0,8), pixel in [0,64)
    const int px = tx*TILE + (pid & (TILE-1));
    const int py = ty*TILE + (pid / TILE);
    const float pu = ((float)px + 0.5f - 48.0f) * FXI;
    const float pv = ((float)py + 0.5f - 48.0f) * FXI;

    const int per = (cnt + NSEG - 1) / NSEG;
    const int sA = min(seg * per, cnt);
    const int sB = min(sA + per, cnt);

    float T = 1.0f, cr = 0.0f, cg = 0.0f, cb = 0.0f;
    #pragma unroll 2
    for (int s = sA; s < sB; s++) {
        float4 a0 = g0[s];
        float4 a1 = g1[s];
        float4 a2 = g2[s];
        float dx = pu - a0.x;
        float dy = pv - a0.y;
        float pw = dx*(a0.z*dx + a0.w*dy) + a1.x*dy*dy;   // log2-scaled power
        float al = fminf(a1.y * __builtin_amdgcn_exp2f(pw), 0.99f);
        float w = T * al;
        cr += w * a1.z;
        cg += w * a1.w;
        cb += w * a2.x;
        T *= (1.0f - al);
    }
    pix[t] = make_float4(cr, cg, cb, T);
    __syncthreads();

    // ---- merge the 8 depth segments front-to-back (64 threads) ----
    if (t < TILE*TILE) {
        float orr = 0.0f, og = 0.0f, ob = 0.0f, T2 = 1.0f;
        #pragma unroll
        for (int s = 0; s < NSEG; s++) {
            float4 P = pix[s*64 + t];
            orr += T2 * P.x;
            og  += T2 * P.y;
            ob  += T2 * P.z;
            T2  *= P.w;
        }
        int pixel = py * IMW + px;
        out[pixel*3+0] = orr;
        out[pixel*3+1] = og;
        out[pixel*3+2] = ob;
    }
}

extern "C" void kernel_launch(void* const* d_in, const int* in_sizes, int n_in,
                              void* d_out, int out_size, void* d_ws, size_t ws_size,
                              hipStream_t stream) {
    const float* pos   = (const float*)d_in[0];
    const float* rgb   = (const float*)d_in[1];
    const float* opa   = (const float*)d_in[2];
    const float* quat  = (const float*)d_in[3];
    const float* scale = (const float*)d_in[4];
    const float* rot   = (const float*)d_in[5];
    const float* tran  = (const float*)d_in[6];
    float* out = (float*)d_out;

    float4* un4   = (float4*)d_ws;      // 4096*3 float4
    float4* ucull = un4 + N_G*3;        // 4096 float4

    preprocess_k<<<N_G/256, 256, 0, stream>>>(pos, rgb, opa, quat, scale, rot, tran,
                                              un4, ucull);
    render_k<<<NTILE, NTHR, 0, stream>>>(un4, ucull, out);
}

// Round 8
// 17.674 us; speedup vs baseline: 7.1768x; 1.1175x over previous
//
#include <hip/hip_runtime.h>
#include <math.h>

#define N_G   4096
#define IMW   96
#define TILE  8             // 8x8 px tiles
#define TILES_X 12
#define NTILE (TILES_X*TILES_X)   // 144
#define NTHR  512           // 8 waves per block
#define NW    (NTHR/64)     // 8 waves
#define NSEG  8             // threads per pixel (depth segments)
#define BCAP  1536          // max bound-phase survivors per tile
#define CAP   512           // max exact survivors per tile
#define FXI   (1.0f/96.0f)
#define NEARP 0.3f
#define EPSV  1e-8f
#define LOG2E 1.4426950408889634f
#define LN2   0.6931471805599453f
#define CULL_K 26.0f        // drop alpha < opa * 2^-26 within tile

// Single kernel: one block per 8x8 tile.
// Phase A: cheap conservative cull bound for all 4096 gaussians -> compact.
// Phase B: exact params + exact cull for bound-survivors only -> compact.
// Phase C: in-place rank sort by (depth_key, order). Phase D: 8-way
// depth-segmented composite. Phase E: merge + store.
__global__ __launch_bounds__(NTHR, 1) void splat_k(
    const float* __restrict__ pos, const float* __restrict__ rgb,
    const float* __restrict__ opa, const float* __restrict__ quat,
    const float* __restrict__ scale, const float* __restrict__ rot,
    const float* __restrict__ tran, float* __restrict__ out)
{
    __shared__ unsigned int bl[BCAP];          // bound survivors (gi), gi-ascending
    __shared__ unsigned long long skey[CAP];   // (key_bits<<32)|slot
    __shared__ float4 g0[CAP], g1[CAP], g2[CAP];
    __shared__ float4 pix[NTHR];
    __shared__ int wsum[NW];

    const int t = threadIdx.x;
    const int tile = blockIdx.x;
    const int tx = tile % TILES_X, ty = tile / TILES_X;
    const float u0 = ((float)(tx*TILE) + 0.5f - 48.0f) * FXI;
    const float u1 = u0 + (TILE-1) * FXI;
    const float v0 = ((float)(ty*TILE) + 0.5f - 48.0f) * FXI;
    const float v1 = v0 + (TILE-1) * FXI;
    const int wid = t >> 6, lane = t & 63;

    float R00=rot[0],R01=rot[1],R02=rot[2];
    float R10=rot[3],R11=rot[4],R12=rot[5];
    float R20=rot[6],R21=rot[7],R22=rot[8];
    float t0=tran[0], t1=tran[1], t2=tran[2];

    // ---- Phase A: cheap conservative bound cull over all gaussians ----
    int bcnt = 0;
    #pragma unroll
    for (int st = 0; st < N_G/NTHR; st++) {
        int gi = st*NTHR + t;
        float p0=pos[gi*3+0], p1=pos[gi*3+1], p2=pos[gi*3+2];
        float o = opa[gi];
        float s0=scale[gi*3+0], s1=scale[gi*3+1], s2=scale[gi*3+2];

        float x = R00*p0 + R01*p1 + R02*p2 + t0;
        float y = R10*p0 + R11*p1 + R12*p2 + t1;
        float z = R20*p0 + R21*p1 + R22*p2 + t2;
        float invz = 1.0f/z;
        float mu = x*invz, mv = y*invz;

        float J02 = -x*invz*invz, J12 = -y*invz*invz;
        float JW00 = invz*R00 + J02*R20;
        float JW01 = invz*R01 + J02*R21;
        float JW02 = invz*R02 + J02*R22;
        float JW10 = invz*R10 + J12*R20;
        float JW11 = invz*R11 + J12*R21;
        float JW12 = invz*R12 + J12*R22;
        float fn = JW00*JW00 + JW01*JW01 + JW02*JW02
                 + JW10*JW10 + JW11*JW11 + JW12*JW12;
        float smax = fmaxf(fmaxf(fabsf(s0), fabsf(s1)), fabsf(s2)) + 1e-4f;
        // lam_max(cov2d + EPS I) <= fn*smax^2 + EPS  (R orthonormal)
        float lmax = fn*smax*smax + EPSV;
        // log2(opa_eff) <= min(0, o*log2e); +1 margin, 1.02 slop for fp error
        float amp = CULL_K + 1.0f + fminf(0.0f, o*LOG2E);
        float r2b = amp * lmax * (2.0f*LN2) * 1.02f;

        float cu = fminf(fmaxf(mu, u0), u1);
        float cv = fminf(fmaxf(mv, v0), v1);
        float ddx = mu - cu, ddy = mv - cv;
        bool flag = (z > NEARP) && (amp > 0.0f) && (ddx*ddx + ddy*ddy <= r2b);

        unsigned long long m = __ballot(flag);
        if (lane == 0) wsum[wid] = __popcll(m);
        __syncthreads();
        int base = bcnt, tot = 0;
        #pragma unroll
        for (int w = 0; w < NW; w++) { int c = wsum[w]; if (w < wid) base += c; tot += c; }
        if (flag) {
            int p = base + __popcll(m & ((1ull << lane) - 1ull));
            if (p < BCAP) bl[p] = (unsigned int)gi;
        }
        bcnt += tot;
        __syncthreads();
    }
    if (bcnt > BCAP) bcnt = BCAP;

    // ---- Phase B: exact params + exact cull for bound-survivors ----
    int cnt = 0;
    for (int s0i = 0; s0i < bcnt; s0i += NTHR) {
        int s = s0i + t;
        bool flag = false;
        float4 o0, o1, o2; float rr = 0.0f;
        if (s < bcnt) {
            int gi = bl[s];
            float p0=pos[gi*3+0], p1=pos[gi*3+1], p2=pos[gi*3+2];
            float x = R00*p0 + R01*p1 + R02*p2 + t0;
            float y = R10*p0 + R11*p1 + R12*p2 + t1;
            float z = R20*p0 + R21*p1 + R22*p2 + t2;
            rr = sqrtf(x*x + y*y + z*z);
            float invz = 1.0f/z;
            float mu = x*invz, mv = y*invz;

            float J02 = -x*invz*invz, J12 = -y*invz*invz;
            float JW00 = invz*R00 + J02*R20;
            float JW01 = invz*R01 + J02*R21;
            float JW02 = invz*R02 + J02*R22;
            float JW10 = invz*R10 + J12*R20;
            float JW11 = invz*R11 + J12*R21;
            float JW12 = invz*R12 + J12*R22;

            float qw=quat[gi*4+0], qx=quat[gi*4+1], qy=quat[gi*4+2], qz=quat[gi*4+3];
            float qn = sqrtf(qw*qw+qx*qx+qy*qy+qz*qz) + 1e-12f;
            float qi = 1.0f/qn;
            qw*=qi; qx*=qi; qy*=qi; qz*=qi;
            float Q00=1.f-2.f*(qy*qy+qz*qz), Q01=2.f*(qx*qy-qw*qz), Q02=2.f*(qx*qz+qw*qy);
            float Q10=2.f*(qx*qy+qw*qz), Q11=1.f-2.f*(qx*qx+qz*qz), Q12=2.f*(qy*qz-qw*qx);
            float Q20=2.f*(qx*qz-qw*qy), Q21=2.f*(qy*qz+qw*qx), Q22=1.f-2.f*(qx*qx+qy*qy);

            float sa=fabsf(scale[gi*3+0])+1e-4f;
            float sb=fabsf(scale[gi*3+1])+1e-4f;
            float sc=fabsf(scale[gi*3+2])+1e-4f;
            float A00=Q00*sa,A01=Q01*sb,A02=Q02*sc;
            float A10=Q10*sa,A11=Q11*sb,A12=Q12*sc;
            float A20=Q20*sa,A21=Q21*sb,A22=Q22*sc;
            float C00=A00*A00+A01*A01+A02*A02;
            float C01=A00*A10+A01*A11+A02*A12;
            float C02=A00*A20+A01*A21+A02*A22;
            float C11=A10*A10+A11*A11+A12*A12;
            float C12=A10*A20+A11*A21+A12*A22;
            float C22=A20*A20+A21*A21+A22*A22;
            float M00=JW00*C00+JW01*C01+JW02*C02;
            float M01=JW00*C01+JW01*C11+JW02*C12;
            float M02=JW00*C02+JW01*C12+JW02*C22;
            float M10=JW10*C00+JW11*C01+JW12*C02;
            float M11=JW10*C01+JW11*C11+JW12*C12;
            float M12=JW10*C02+JW11*C12+JW12*C22;
            float a  = M00*JW00+M01*JW01+M02*JW02 + EPSV;
            float d  = M10*JW10+M11*JW11+M12*JW12 + EPSV;
            float bb = 0.5f*((M00*JW10+M01*JW11+M02*JW12)+(M10*JW00+M11*JW01+M12*JW02));
            float invdet = 1.0f/(a*d - bb*bb);
            float iaP = -0.5f*d*invdet*LOG2E;
            float ibP =  bb*invdet*LOG2E;
            float idP = -0.5f*a*invdet*LOG2E;

            float sig_o = 1.0f/(1.0f+__expf(-opa[gi]));
            float opa_eff = (z > NEARP) ? sig_o : 0.0f;

            // exact conservative cull radius^2 (identical to round 7)
            float q00 = -iaP, q01 = -0.5f*ibP, q11 = -idP;
            float df = q00 - q11;
            float lam = 0.5f*((q00 + q11) - sqrtf(df*df + 4.0f*q01*q01));
            lam = fmaxf(lam, 1e-20f);
            float r2 = (CULL_K + log2f(opa_eff)) / lam;

            float cu = fminf(fmaxf(mu, u0), u1);
            float cv = fminf(fmaxf(mv, v0), v1);
            float ddx = mu - cu, ddy = mv - cv;
            flag = (ddx*ddx + ddy*ddy) <= r2;

            if (flag) {
                float c0 = 1.0f/(1.0f+__expf(-rgb[gi*3+0]));
                float c1 = 1.0f/(1.0f+__expf(-rgb[gi*3+1]));
                float c2 = 1.0f/(1.0f+__expf(-rgb[gi*3+2]));
                o0 = make_float4(mu, mv, iaP, ibP);
                o1 = make_float4(idP, opa_eff, c0, c1);
                o2 = make_float4(c2, 0.0f, 0.0f, 0.0f);
            }
        }
        unsigned long long m = __ballot(flag);
        if (lane == 0) wsum[wid] = __popcll(m);
        __syncthreads();
        int base = cnt, tot = 0;
        #pragma unroll
        for (int w = 0; w < NW; w++) { int c = wsum[w]; if (w < wid) base += c; tot += c; }
        if (flag) {
            int p = base + __popcll(m & ((1ull << lane) - 1ull));
            if (p < CAP) {
                g0[p] = o0; g1[p] = o1; g2[p] = o2;
                // slot order == bl order == gi order -> stable tie-break
                skey[p] = ((unsigned long long)__float_as_uint(rr) << 32)
                          | (unsigned int)p;
            }
        }
        cnt += tot;
        __syncthreads();
    }
    if (cnt > CAP) cnt = CAP;

    // ---- Phase C: in-place rank sort by (key_bits, slot) ----
    unsigned long long v = 0; int r = -1;
    if (t < cnt) {
        v = skey[t];
        r = 0;
        for (int j = 0; j < cnt; j++) r += (skey[j] < v) ? 1 : 0;
    }
    __syncthreads();
    if (r >= 0) skey[r] = v;
    __syncthreads();

    // ---- Phase D: 8-way depth-segmented composite ----
    const int seg = t >> 6, pid = t & 63;
    const int px = tx*TILE + (pid & (TILE-1));
    const int py = ty*TILE + (pid / TILE);
    const float pu = ((float)px + 0.5f - 48.0f) * FXI;
    const float pv = ((float)py + 0.5f - 48.0f) * FXI;

    const int per = (cnt + NSEG - 1) / NSEG;
    const int sA = min(seg * per, cnt);
    const int sB = min(sA + per, cnt);

    float T = 1.0f, cr = 0.0f, cg = 0.0f, cb = 0.0f;
    #pragma unroll 2
    for (int s = sA; s < sB; s++) {
        int slot = (int)(skey[s] & 0xffffffffu);
        float4 a0 = g0[slot];
        float4 a1 = g1[slot];
        float4 a2 = g2[slot];
        float dx = pu - a0.x;
        float dy = pv - a0.y;
        float pw = dx*(a0.z*dx + a0.w*dy) + a1.x*dy*dy;   // log2-scaled power
        float al = fminf(a1.y * __builtin_amdgcn_exp2f(pw), 0.99f);
        float w = T * al;
        cr += w * a1.z;
        cg += w * a1.w;
        cb += w * a2.x;
        T *= (1.0f - al);
    }
    pix[t] = make_float4(cr, cg, cb, T);
    __syncthreads();

    // ---- Phase E: merge 8 depth segments front-to-back, store ----
    if (t < TILE*TILE) {
        float orr = 0.0f, og = 0.0f, ob = 0.0f, T2 = 1.0f;
        #pragma unroll
        for (int s = 0; s < NSEG; s++) {
            float4 P = pix[s*64 + t];
            orr += T2 * P.x;
            og  += T2 * P.y;
            ob  += T2 * P.z;
            T2  *= P.w;
        }
        int pixel = py * IMW + px;
        out[pixel*3+0] = orr;
        out[pixel*3+1] = og;
        out[pixel*3+2] = ob;
    }
}

extern "C" void kernel_launch(void* const* d_in, const int* in_sizes, int n_in,
                              void* d_out, int out_size, void* d_ws, size_t ws_size,
                              hipStream_t stream) {
    const float* pos   = (const float*)d_in[0];
    const float* rgb   = (const float*)d_in[1];
    const float* opa   = (const float*)d_in[2];
    const float* quat  = (const float*)d_in[3];
    const float* scale = (const float*)d_in[4];
    const float* rot   = (const float*)d_in[5];
    const float* tran  = (const float*)d_in[6];
    float* out = (float*)d_out;

    splat_k<<<NTILE, NTHR, 0, stream>>>(pos, rgb, opa, quat, scale, rot, tran, out);
}